// Round 1
// baseline (1909.453 us; speedup 1.0000x reference)
//
#include <hip/hip_runtime.h>
#include <hip/hip_bf16.h>
#include <stdint.h>

// Problem constants
#define D 1280
#define ND 6
#define BATCH 1024
#define ROWSTRIDE (ND*D)          // 7680 elements per batch row of (B,6,D)
#define WELEM (D*D)               // 1,638,400
#define WIOF(e) ((e)*WELEM)
#define WOOF(e) ((6+(e))*WELEM)
#define WROF (12*WELEM)
#define WZOF (15*WELEM)
#define WTOF (18*WELEM)
#define WTOT (21*WELEM)           // 34,406,400 bf16 elems
#define ABUF (BATCH*ROWSTRIDE)    // 7,864,320
#define AINO (ABUF)
#define AOUTO (2*ABUF)
#define RGO (3*ABUF)
#define S3D (3*D)

typedef unsigned int u32;
typedef unsigned short u16;
typedef __bf16 bf16x8 __attribute__((ext_vector_type(8)));
typedef float f32x4 __attribute__((ext_vector_type(4)));

struct Term { int a_off; int b_off; int b_stride; int bias_off; };
struct Job  { int nterms; int epi; int node; int flag; Term t[3]; };

// epi: 0 = phase1 (write AIN/AOUT bf16, + per-term bias rows)
//      1 = r: sigmoid(acc+b_r) * gx -> rg (bf16)
//      2 = z: sigmoid(acc+b_z) -> fp32
//      3 = tpart: acc -> fp32
//      4 = final: tanh(acc + b_t [+ tpart]); gx = (1-z)gx + z*h; write gx fp32 + gxb bf16
// Edges (src,et,tgt) 0-based: (0,0,1)(0,1,2)(0,2,3)(1,3,2)(1,4,3)(2,5,3)
__constant__ Job JOBS[28] = {
  // ---- phase1 (jobs 0..5): flag 0 -> b_in/AIN, 1 -> b_out/AOUT
  {1,0,1,0, {{0*D, WIOF(0), D, 0*D},{0,0,0,0},{0,0,0,0}}},
  {2,0,2,0, {{0*D, WIOF(1), D, 1*D},{1*D, WIOF(3), D, 3*D},{0,0,0,0}}},
  {3,0,3,0, {{0*D, WIOF(2), D, 2*D},{1*D, WIOF(4), D, 4*D},{2*D, WIOF(5), D, 5*D}}},
  {3,0,0,1, {{1*D, WOOF(0), D, 0*D},{2*D, WOOF(1), D, 1*D},{3*D, WOOF(2), D, 2*D}}},
  {2,0,1,1, {{2*D, WOOF(3), D, 3*D},{3*D, WOOF(4), D, 4*D},{0,0,0,0}}},
  {1,0,2,1, {{3*D, WOOF(5), D, 5*D},{0,0,0,0},{0,0,0,0}}},
  // ---- phase2 r (jobs 6..11)
  {2,1,0,0, {{AOUTO+0*D, WROF+1*D, S3D, 0},{0*D, WROF+2*D, S3D, 0},{0,0,0,0}}},
  {3,1,1,0, {{AINO+1*D, WROF+0*D, S3D, 0},{AOUTO+1*D, WROF+1*D, S3D, 0},{1*D, WROF+2*D, S3D, 0}}},
  {3,1,2,0, {{AINO+2*D, WROF+0*D, S3D, 0},{AOUTO+2*D, WROF+1*D, S3D, 0},{2*D, WROF+2*D, S3D, 0}}},
  {2,1,3,0, {{AINO+3*D, WROF+0*D, S3D, 0},{3*D, WROF+2*D, S3D, 0},{0,0,0,0}}},
  {1,1,4,0, {{4*D, WROF+2*D, S3D, 0},{0,0,0,0},{0,0,0,0}}},
  {1,1,5,0, {{5*D, WROF+2*D, S3D, 0},{0,0,0,0},{0,0,0,0}}},
  // ---- phase2 z (jobs 12..17)
  {2,2,0,0, {{AOUTO+0*D, WZOF+1*D, S3D, 0},{0*D, WZOF+2*D, S3D, 0},{0,0,0,0}}},
  {3,2,1,0, {{AINO+1*D, WZOF+0*D, S3D, 0},{AOUTO+1*D, WZOF+1*D, S3D, 0},{1*D, WZOF+2*D, S3D, 0}}},
  {3,2,2,0, {{AINO+2*D, WZOF+0*D, S3D, 0},{AOUTO+2*D, WZOF+1*D, S3D, 0},{2*D, WZOF+2*D, S3D, 0}}},
  {2,2,3,0, {{AINO+3*D, WZOF+0*D, S3D, 0},{3*D, WZOF+2*D, S3D, 0},{0,0,0,0}}},
  {1,2,4,0, {{4*D, WZOF+2*D, S3D, 0},{0,0,0,0},{0,0,0,0}}},
  {1,2,5,0, {{5*D, WZOF+2*D, S3D, 0},{0,0,0,0},{0,0,0,0}}},
  // ---- phase2 tpart (jobs 18..21)
  {1,3,0,0, {{AOUTO+0*D, WTOF+1*D, S3D, 0},{0,0,0,0},{0,0,0,0}}},
  {2,3,1,0, {{AINO+1*D, WTOF+0*D, S3D, 0},{AOUTO+1*D, WTOF+1*D, S3D, 0},{0,0,0,0}}},
  {2,3,2,0, {{AINO+2*D, WTOF+0*D, S3D, 0},{AOUTO+2*D, WTOF+1*D, S3D, 0},{0,0,0,0}}},
  {1,3,3,0, {{AINO+3*D, WTOF+0*D, S3D, 0},{0,0,0,0},{0,0,0,0}}},
  // ---- phase3 (jobs 22..27): flag = has tpart
  {1,4,0,1, {{RGO+0*D, WTOF+2*D, S3D, 0},{0,0,0,0},{0,0,0,0}}},
  {1,4,1,1, {{RGO+1*D, WTOF+2*D, S3D, 0},{0,0,0,0},{0,0,0,0}}},
  {1,4,2,1, {{RGO+2*D, WTOF+2*D, S3D, 0},{0,0,0,0},{0,0,0,0}}},
  {1,4,3,1, {{RGO+3*D, WTOF+2*D, S3D, 0},{0,0,0,0},{0,0,0,0}}},
  {1,4,4,0, {{RGO+4*D, WTOF+2*D, S3D, 0},{0,0,0,0},{0,0,0,0}}},
  {1,4,5,0, {{RGO+5*D, WTOF+2*D, S3D, 0},{0,0,0,0},{0,0,0,0}}},
};

__device__ __forceinline__ void gload16(const void* g, void* l) {
  __builtin_amdgcn_global_load_lds((const __attribute__((address_space(1))) u32*)g,
                                   (__attribute__((address_space(3))) u32*)l, 16, 0, 0);
}
__device__ __forceinline__ float sig_(float x){ return 1.f/(1.f+__expf(-x)); }
__device__ __forceinline__ float tanh_(float x){ float e=__expf(2.f*x); return 1.f-2.f/(e+1.f); }

__device__ __forceinline__ u16 f2b(float f){ __hip_bfloat16 v = __float2bfloat16(f); return *(u16*)&v; }

// Batched GEMM: C_job = sum_terms A_term @ B_term, A tiles (128 x 64) from act (row stride 7680),
// B tiles (128 x 64) from transposed bf16 weights (row = output col n, cols = k).
__global__ __launch_bounds__(256)
void gemm_batched(u16* act, const u16* __restrict__ wb,
                  float* __restrict__ gx, float* __restrict__ zbuf, float* __restrict__ tp,
                  const float* __restrict__ b_in, const float* __restrict__ b_out,
                  const float* __restrict__ b_r, const float* __restrict__ b_z,
                  const float* __restrict__ b_t, int job_base) {
  const int bid = blockIdx.x;
  const Job jb = JOBS[job_base + bid/80];
  const int t80 = bid % 80;
  const int m0 = (t80/10)*128;
  const int n0 = (t80%10)*128;
  const int tid = threadIdx.x;
  const int lane = tid & 63;
  const int w = tid >> 6;
  const int wm = ((w>>1)<<6);
  const int wn = ((w&1)<<6);

  __shared__ __align__(16) u16 lsA[128*64];
  __shared__ __align__(16) u16 lsB[128*64];

  f32x4 acc[4][4];
#pragma unroll
  for (int i=0;i<4;i++)
#pragma unroll
    for (int j=0;j<4;j++) acc[i][j] = (f32x4)(0.0f);

  const int srow = lane>>3;          // staging: 8 rows / instr
  const int scol = (lane&7)*8;       // 8 bf16 = 16B per lane

  for (int term=0; term<jb.nterms; ++term) {
    const u16* Ab = act + jb.t[term].a_off;
    const u16* Bb = wb  + jb.t[term].b_off;
    const int bstr = jb.t[term].b_stride;
    for (int kt=0; kt<20; ++kt) {
      const int kk = kt*64;
#pragma unroll
      for (int i=0;i<4;i++) {
        const int rr = w*32 + i*8 + srow;
        gload16(Ab + (size_t)(m0+rr)*ROWSTRIDE + kk + scol, &lsA[(w*32+i*8)*64]);
        gload16(Bb + (size_t)(n0+rr)*bstr      + kk + scol, &lsB[(w*32+i*8)*64]);
      }
      __syncthreads();
#pragma unroll
      for (int ks=0; ks<2; ++ks) {
        bf16x8 af[4], bfr[4];
#pragma unroll
        for (int i=0;i<4;i++) {
          af[i]  = *(const bf16x8*)&lsA[(wm + i*16 + (lane&15))*64 + ks*32 + (lane>>4)*8];
          bfr[i] = *(const bf16x8*)&lsB[(wn + i*16 + (lane&15))*64 + ks*32 + (lane>>4)*8];
        }
#pragma unroll
        for (int i=0;i<4;i++)
#pragma unroll
          for (int j=0;j<4;j++)
            acc[i][j] = __builtin_amdgcn_mfma_f32_16x16x32_bf16(af[i], bfr[j], acc[i][j], 0,0,0);
      }
      __syncthreads();
    }
  }

  // Epilogue. C fragment mapping (16x16x32 bf16): col = lane&15, row = (lane>>4)*4 + reg.
  const int r0 = m0 + wm + ((lane>>4)<<2);
  const int c0 = n0 + wn + (lane&15);
  const int node = jb.node;

  if (jb.epi == 0) {
    const float* bias = jb.flag ? b_out : b_in;
    u16* outp = act + (jb.flag ? AOUTO : AINO) + node*D;
    float bsum[4];
#pragma unroll
    for (int j=0;j<4;j++) {
      float s = 0.f;
      for (int t2=0;t2<jb.nterms;t2++) s += bias[jb.t[t2].bias_off + c0 + j*16];
      bsum[j] = s;
    }
#pragma unroll
    for (int i=0;i<4;i++)
#pragma unroll
      for (int j=0;j<4;j++)
#pragma unroll
        for (int r=0;r<4;r++) {
          int row = r0 + i*16 + r, col = c0 + j*16;
          outp[(size_t)row*ROWSTRIDE + col] = f2b(acc[i][j][r] + bsum[j]);
        }
  } else if (jb.epi == 1) {
#pragma unroll
    for (int i=0;i<4;i++)
#pragma unroll
      for (int j=0;j<4;j++)
#pragma unroll
        for (int r=0;r<4;r++) {
          int row = r0 + i*16 + r, col = c0 + j*16;
          size_t idx = (size_t)row*ROWSTRIDE + node*D + col;
          float rr = sig_(acc[i][j][r] + b_r[col]);
          act[RGO + idx] = f2b(rr * gx[idx]);
        }
  } else if (jb.epi == 2) {
#pragma unroll
    for (int i=0;i<4;i++)
#pragma unroll
      for (int j=0;j<4;j++)
#pragma unroll
        for (int r=0;r<4;r++) {
          int row = r0 + i*16 + r, col = c0 + j*16;
          size_t idx = (size_t)row*ROWSTRIDE + node*D + col;
          zbuf[idx] = sig_(acc[i][j][r] + b_z[col]);
        }
  } else if (jb.epi == 3) {
#pragma unroll
    for (int i=0;i<4;i++)
#pragma unroll
      for (int j=0;j<4;j++)
#pragma unroll
        for (int r=0;r<4;r++) {
          int row = r0 + i*16 + r, col = c0 + j*16;
          size_t idx = (size_t)row*ROWSTRIDE + node*D + col;
          tp[idx] = acc[i][j][r];
        }
  } else {
#pragma unroll
    for (int i=0;i<4;i++)
#pragma unroll
      for (int j=0;j<4;j++)
#pragma unroll
        for (int r=0;r<4;r++) {
          int row = r0 + i*16 + r, col = c0 + j*16;
          size_t idx = (size_t)row*ROWSTRIDE + node*D + col;
          float tv = acc[i][j][r] + b_t[col] + (jb.flag ? tp[idx] : 0.f);
          float h = tanh_(tv);
          float zv = zbuf[idx];
          float g = gx[idx];
          float ng = (1.f - zv)*g + zv*h;
          gx[idx] = ng;
          act[idx] = f2b(ng);   // gxb for next step
        }
  }
}

// Transpose-convert all weights fp32 -> bf16 transposed layout (rows = output col n, cols = k).
__global__ void conv_weights(const float* __restrict__ wi, const float* __restrict__ wo,
                             const float* __restrict__ wr, const float* __restrict__ wz,
                             const float* __restrict__ wt, u16* __restrict__ wb) {
  int bid = blockIdx.x;
  int base = 0; int j = 0;
  for (; j < 15; ++j) {
    int R_ = (j < 12) ? 1280 : 3840;
    int tiles = (R_/32)*40;
    if (bid < base + tiles) break;
    base += tiles;
  }
  const int R = (j < 12) ? 1280 : 3840;
  const int C = 1280;
  const float* src; int doff;
  if (j < 6)        { src = wi + (size_t)j*WELEM;     doff = WIOF(j); }
  else if (j < 12)  { src = wo + (size_t)(j-6)*WELEM; doff = WOOF(j-6); }
  else if (j == 12) { src = wr;                       doff = WROF; }
  else if (j == 13) { src = wz;                       doff = WZOF; }
  else              { src = wt;                       doff = WTOF; }
  int tt = bid - base;
  int tr = tt / 40, tc = tt % 40;
  __shared__ float tile[32][33];
  int tx = threadIdx.x, ty = threadIdx.y;
#pragma unroll
  for (int k=0;k<4;k++)
    tile[ty+8*k][tx] = src[(size_t)(tr*32+ty+8*k)*C + tc*32+tx];
  __syncthreads();
  u16* dst = wb + doff;
#pragma unroll
  for (int k=0;k<4;k++)
    dst[(size_t)(tc*32+ty+8*k)*R + tr*32+tx] = f2b(tile[tx][ty+8*k]);
}

__global__ void init_gx(const float* __restrict__ x, float* __restrict__ gx, u16* __restrict__ gxb) {
  for (size_t i = (size_t)blockIdx.x*blockDim.x + threadIdx.x; i < (size_t)ABUF;
       i += (size_t)gridDim.x*blockDim.x) {
    float v = x[i];
    gx[i] = v;
    gxb[i] = f2b(v);
  }
}

// out[b, d*6+n] = gx[b, n, d]
__global__ void final_out(const float* __restrict__ gx, float* __restrict__ out) {
  int b = blockIdx.x;
  const float* g = gx + (size_t)b*ROWSTRIDE;
  float* o = out + (size_t)b*ROWSTRIDE;
  for (int jj = threadIdx.x; jj < ROWSTRIDE; jj += blockDim.x) {
    int n = jj % ND, d = jj / ND;
    o[jj] = g[n*D + d];
  }
}

extern "C" void kernel_launch(void* const* d_in, const int* in_sizes, int n_in,
                              void* d_out, int out_size, void* d_ws, size_t ws_size,
                              hipStream_t stream) {
  (void)in_sizes; (void)n_in; (void)out_size; (void)ws_size;
  const float* x  = (const float*)d_in[0];
  const float* Wi = (const float*)d_in[2];
  const float* bi = (const float*)d_in[3];
  const float* Wo = (const float*)d_in[4];
  const float* bo = (const float*)d_in[5];
  const float* Wr = (const float*)d_in[6];
  const float* br = (const float*)d_in[7];
  const float* Wz = (const float*)d_in[8];
  const float* bz = (const float*)d_in[9];
  const float* Wt = (const float*)d_in[10];
  const float* bt = (const float*)d_in[11];
  float* out = (float*)d_out;

  u16* wb  = (u16*)d_ws;                       // 21*WELEM bf16
  u16* act = wb + WTOT;                        // 4*ABUF bf16: [gxb | AIN | AOUT | rg]
  float* gx = (float*)(act + (size_t)4*ABUF);  // fp32 master state
  float* zb = gx + ABUF;
  float* tp = zb + ABUF;

  conv_weights<<<33600, dim3(32,8,1), 0, stream>>>(Wi, Wo, Wr, Wz, Wt, wb);
  init_gx<<<2048, 256, 0, stream>>>(x, gx, act);
  for (int s = 0; s < 5; ++s) {
    gemm_batched<<<480, 256, 0, stream>>>(act, wb, gx, zb, tp, bi, bo, br, bz, bt, 0);
    gemm_batched<<<1280,256, 0, stream>>>(act, wb, gx, zb, tp, bi, bo, br, bz, bt, 6);
    gemm_batched<<<480, 256, 0, stream>>>(act, wb, gx, zb, tp, bi, bo, br, bz, bt, 22);
  }
  final_out<<<BATCH, 256, 0, stream>>>(gx, out);
}